// Round 1
// baseline (154.199 us; speedup 1.0000x reference)
//
#include <hip/hip_runtime.h>

#define NB 32
#define NPRED 65536
#define NGT 64
#define BLK 256
#define SLICES 64
#define PPT 4                  // preds per thread; block covers 1024 preds
#define NCB 128                // cumulative bins of 5px
#define CBIN_SCALE 0.2f        // 1/5

#define POS_THR 0.5f
#define NEG_THR 0.4f
#define SCAT_THR 0.1f
#define EPSF 1e-6f

// ---------- exact-op helpers ----------
// Comparison-feeding arithmetic (iou) must be bit-exact vs NumPy fp32 (no FMA
// contraction, IEEE div). Sum-only terms (focal/giou weights) tolerate ulp drift.

__device__ __forceinline__ int cbin(float x) {
    int bi = (int)(x * CBIN_SCALE);         // trunc; monotone non-decreasing
    return max(0, min(NCB - 1, bi));        // clamp keeps monotone -> superset safe
}

__device__ __forceinline__ float focal_shared(float l, bool pos) {
    float e  = expf(-fabsf(l));
    float lg = log1pf(e);
    float rp = 1.f / (1.f + e);              // sigmoid(|l|)
    float p  = (l >= 0.f) ? rp : (1.f - rp); // sigmoid(l); sum-only term
    if (pos) { float q = 1.f - p; return 0.25f * q * q * ((fmaxf(l, 0.f) - l) + lg); }
    return 0.75f * p * p * (fmaxf(l, 0.f) + lg);
}

__device__ __forceinline__ float giou_term(float px1, float py1, float px2, float py2,
                                           float gx1, float gy1, float gx2, float gy2) {
    float x1 = fmaxf(px1, gx1), y1 = fmaxf(py1, gy1);
    float x2 = fminf(px2, gx2), y2 = fminf(py2, gy2);
    float dx = fmaxf(__fsub_rn(x2, x1), 0.f);
    float dy = fmaxf(__fsub_rn(y2, y1), 0.f);
    float inter = __fmul_rn(dx, dy);
    float ap = __fmul_rn(__fsub_rn(px2, px1), __fsub_rn(py2, py1));
    float ag = __fmul_rn(__fsub_rn(gx2, gx1), __fsub_rn(gy2, gy1));
    float uni = __fsub_rn(__fadd_rn(ap, ag), inter);
    float iou = __fdiv_rn(inter, fmaxf(uni, EPSF));
    float ex1 = fminf(px1, gx1), ey1 = fminf(py1, gy1);
    float ex2 = fmaxf(px2, gx2), ey2 = fmaxf(py2, gy2);
    float enc = __fmul_rn(__fsub_rn(ex2, ex1), __fsub_rn(ey2, ey1));
    float giou = __fsub_rn(iou, __fdiv_rn(__fsub_rn(enc, uni), fmaxf(enc, EPSF)));
    return __fsub_rn(1.f, giou);
}

// ---------- Pass A: per-slice partials, NO global atomics, NO pre-zero ----------
// keysP layout: [NB][NGT][SLICES] ullong  (every entry written unconditionally)
// partS layout: [NB][SLICES] float4 {sum_fl, sum_gt, bitcast(v|p<<16), 0}

__global__ __launch_bounds__(BLK) void passA(
    const float* __restrict__ pred, const float* __restrict__ gt,
    unsigned long long* __restrict__ keysP,
    float4* __restrict__ partS)
{
    const int b = blockIdx.y;
    const int slice = blockIdx.x;
    const int tid = threadIdx.x;
    const int lane = tid & 63;
    const int wv = tid >> 6;

    // SoA gt (65th entry = zero dummy for branchless inline slots)
    __shared__ float sgx1[NGT + 1], sgy1[NGT + 1], sgx2[NGT + 1], sgy2[NGT + 1], sgar[NGT + 1];
    __shared__ unsigned long long skey[NGT];       // 512 B
    // cumulative candidate masks: [0]=le_x1 (prefix), [1]=ge_x2 (suffix),
    //                             [2]=le_y1 (prefix), [3]=ge_y2 (suffix)
    __shared__ unsigned long long cums[4][NCB];    // 4 KiB
    __shared__ float rfl[BLK / 64], rgt[BLK / 64];
    __shared__ int rvp[BLK / 64];

    // ---- pred loads first: 5 aligned float4 per thread, in flight during setup ----
    const unsigned base_n = (unsigned)(slice * (BLK * PPT));
    const float4* src4 = (const float4*)(pred + (size_t)b * NPRED * 5 + (size_t)base_n * 5)
                         + (size_t)tid * 5;
    float4 q0 = src4[0], q1 = src4[1], q2 = src4[2], q3 = src4[3], q4 = src4[4];

    // ---- gt setup ----
    const float4* gtb = (const float4*)(gt + (size_t)b * NGT * 4);
    float4 gmine;
    if (tid < NGT) gmine = gtb[tid];
    // zero the 4 point arrays (512 ullong, 2 per thread)
    ((unsigned long long*)cums)[tid] = 0ULL;
    ((unsigned long long*)cums)[tid + BLK] = 0ULL;
    if (tid < NGT) {
        sgx1[tid] = gmine.x; sgy1[tid] = gmine.y;
        sgx2[tid] = gmine.z; sgy2[tid] = gmine.w;
        sgar[tid] = __fmul_rn(__fsub_rn(gmine.z, gmine.x), __fsub_rn(gmine.w, gmine.y));
        skey[tid] = 0ULL;
    } else if (tid == NGT) {
        sgx1[NGT] = 0.f; sgy1[NGT] = 0.f; sgx2[NGT] = 0.f; sgy2[NGT] = 0.f; sgar[NGT] = 0.f;
    }
    __syncthreads();

    // point inserts (wave 0 only)
    if (tid < NGT) {
        unsigned long long bit = 1ULL << tid;
        atomicOr(&cums[0][cbin(gmine.x)], bit);   // gx1 -> prefix array
        atomicOr(&cums[1][cbin(gmine.z)], bit);   // gx2 -> suffix array
        atomicOr(&cums[2][cbin(gmine.y)], bit);   // gy1 -> prefix array
        atomicOr(&cums[3][cbin(gmine.w)], bit);   // gy2 -> suffix array
    }
    __syncthreads();

    // wave-parallel cumulative OR: wave wv scans array wv (128 bins, 2/lane).
    {
        unsigned long long v0 = cums[wv][2 * lane];
        unsigned long long v1 = cums[wv][2 * lane + 1];
        unsigned long long v = v0 | v1;
        if ((wv & 1) == 0) {
            // prefix (le): inclusive scan low->high
            #pragma unroll
            for (int off = 1; off < 64; off <<= 1) {
                unsigned long long t = __shfl_up(v, off);
                if (lane >= off) v |= t;
            }
            unsigned long long prev = __shfl_up(v, 1);
            if (lane == 0) prev = 0ULL;
            cums[wv][2 * lane]     = prev | v0;
            cums[wv][2 * lane + 1] = v;
        } else {
            // suffix (ge): inclusive scan high->low
            #pragma unroll
            for (int off = 1; off < 64; off <<= 1) {
                unsigned long long t = __shfl_down(v, off);
                if (lane + off < 64) v |= t;
            }
            unsigned long long nxt = __shfl_down(v, 1);
            if (lane == 63) nxt = 0ULL;
            cums[wv][2 * lane]     = v;
            cums[wv][2 * lane + 1] = v1 | nxt;
        }
    }
    __syncthreads();

    // ---- unpack rows: thread t owns preds 4t..4t+3 (stride-5 in the 20 floats) ----
    const float cxa[PPT] = {q0.x, q1.y, q2.z, q3.w};
    const float cya[PPT] = {q0.y, q1.z, q2.w, q4.x};
    const float wa [PPT] = {q0.z, q1.w, q3.x, q4.y};
    const float ha [PPT] = {q0.w, q2.x, q3.y, q4.z};
    const float oba[PPT] = {q1.x, q2.y, q3.z, q4.w};

    float acc_fl = 0.f, acc_gt = 0.f;
    int acc_vp = 0;   // valid count | pos count<<16

    #pragma unroll
    for (int i = 0; i < PPT; ++i) {
        const float px1 = __fsub_rn(cxa[i], __fmul_rn(wa[i], 0.5f));
        const float py1 = __fsub_rn(cya[i], __fmul_rn(ha[i], 0.5f));
        const float px2 = __fadd_rn(cxa[i], __fmul_rn(wa[i], 0.5f));
        const float py2 = __fadd_rn(cya[i], __fmul_rn(ha[i], 0.5f));
        const float area_p = __fmul_rn(__fsub_rn(px2, px1), __fsub_rn(py2, py1));

        // 4-probe candidate mask (superset of true overlaps; exact gate below)
        unsigned long long m = (cums[1][cbin(px1)] & cums[0][cbin(px2)])
                             & (cums[3][cbin(py1)] & cums[2][cbin(py2)]);

        const unsigned n = base_n + (unsigned)(PPT * tid + i);
        const unsigned long long nkey = (unsigned long long)(~n);

        float best_iou = 0.f;   // zero row -> argmax 0, matches np.argmax
        int best_j = 0;

        // branchless inline-2: dummy index 64 (zero box) -> inter=0 -> no-op
        int j0 = NGT, j1 = NGT;
        if (m) { j0 = __ffsll(m) - 1; m &= m - 1; }
        if (m) { j1 = __ffsll(m) - 1; m &= m - 1; }
        {
            float ax1 = sgx1[j0], ay1 = sgy1[j0], ax2 = sgx2[j0], ay2 = sgy2[j0], aga = sgar[j0];
            float bx1 = sgx1[j1], by1 = sgy1[j1], bx2 = sgx2[j1], by2 = sgy2[j1], agb = sgar[j1];
            float x1 = fmaxf(px1, ax1), y1 = fmaxf(py1, ay1);
            float x2 = fminf(px2, ax2), y2 = fminf(py2, ay2);
            float dx = fmaxf(__fsub_rn(x2, x1), 0.f);
            float dy = fmaxf(__fsub_rn(y2, y1), 0.f);
            float inter = __fmul_rn(dx, dy);
            float uni = __fsub_rn(__fadd_rn(area_p, aga), inter);
            float iou = __fdiv_rn(inter, fmaxf(uni, EPSF));
            iou = (inter > 0.f) ? iou : 0.f;
            if (iou > best_iou) { best_iou = iou; best_j = j0; }
            if (iou > SCAT_THR)
                atomicMax(&skey[j0], (((unsigned long long)__float_as_uint(iou)) << 32) | nkey);

            float X1 = fmaxf(px1, bx1), Y1 = fmaxf(py1, by1);
            float X2 = fminf(px2, bx2), Y2 = fminf(py2, by2);
            float dX = fmaxf(__fsub_rn(X2, X1), 0.f);
            float dY = fmaxf(__fsub_rn(Y2, Y1), 0.f);
            float interB = __fmul_rn(dX, dY);
            float uniB = __fsub_rn(__fadd_rn(area_p, agb), interB);
            float iouB = __fdiv_rn(interB, fmaxf(uniB, EPSF));
            iouB = (interB > 0.f) ? iouB : 0.f;
            if (iouB > best_iou) { best_iou = iouB; best_j = j1; }
            if (iouB > SCAT_THR)
                atomicMax(&skey[j1], (((unsigned long long)__float_as_uint(iouB)) << 32) | nkey);
        }

        // rare remainder (2-way unrolled)
        while (m) {
            int ja = __ffsll(m) - 1; m &= m - 1;
            int jb = -1;
            if (m) { jb = __ffsll(m) - 1; m &= m - 1; }
            int jbc = (jb >= 0) ? jb : NGT;
            float ax1 = sgx1[ja], ay1 = sgy1[ja], ax2 = sgx2[ja], ay2 = sgy2[ja], aga = sgar[ja];
            float bx1 = sgx1[jbc], by1 = sgy1[jbc], bx2 = sgx2[jbc], by2 = sgy2[jbc], agb = sgar[jbc];
            {
                float x1 = fmaxf(px1, ax1), y1 = fmaxf(py1, ay1);
                float x2 = fminf(px2, ax2), y2 = fminf(py2, ay2);
                float dx = fmaxf(__fsub_rn(x2, x1), 0.f);
                float dy = fmaxf(__fsub_rn(y2, y1), 0.f);
                float inter = __fmul_rn(dx, dy);
                if (inter > 0.f) {
                    float uni = __fsub_rn(__fadd_rn(area_p, aga), inter);
                    float iou = __fdiv_rn(inter, fmaxf(uni, EPSF));
                    if (iou > best_iou) { best_iou = iou; best_j = ja; }
                    if (iou > SCAT_THR)
                        atomicMax(&skey[ja], (((unsigned long long)__float_as_uint(iou)) << 32) | nkey);
                }
            }
            if (jb >= 0) {
                float x1 = fmaxf(px1, bx1), y1 = fmaxf(py1, by1);
                float x2 = fminf(px2, bx2), y2 = fminf(py2, by2);
                float dx = fmaxf(__fsub_rn(x2, x1), 0.f);
                float dy = fmaxf(__fsub_rn(y2, y1), 0.f);
                float inter = __fmul_rn(dx, dy);
                if (inter > 0.f) {
                    float uni = __fsub_rn(__fadd_rn(area_p, agb), inter);
                    float iou = __fdiv_rn(inter, fmaxf(uni, EPSF));
                    if (iou > best_iou) { best_iou = iou; best_j = jb; }
                    if (iou > SCAT_THR)
                        atomicMax(&skey[jb], (((unsigned long long)__float_as_uint(iou)) << 32) | nkey);
                }
            }
        }

        const bool pos0   = best_iou > POS_THR;
        const bool negf   = best_iou < NEG_THR;
        const bool valid0 = pos0 || negf;
        if (valid0) acc_fl += focal_shared(oba[i], pos0);
        if (pos0) {
            acc_gt += giou_term(px1, py1, px2, py2,
                                sgx1[best_j], sgy1[best_j], sgx2[best_j], sgy2[best_j]);
        }
        acc_vp += (valid0 ? 1 : 0) | (pos0 ? 0x10000 : 0);
    }

    // one reduction + plain per-slice stores (no global atomics, no pre-zeroed ws)
    for (int off = 32; off; off >>= 1) {
        acc_fl += __shfl_down(acc_fl, off);
        acc_gt += __shfl_down(acc_gt, off);
        acc_vp += __shfl_down(acc_vp, off);
    }
    if (lane == 0) { rfl[wv] = acc_fl; rgt[wv] = acc_gt; rvp[wv] = acc_vp; }
    __syncthreads();   // also orders all skey LDS atomics before the drain
    if (tid == 0) {
        float sfl = 0.f, sgt2 = 0.f; int svp = 0;
        #pragma unroll
        for (int i = 0; i < BLK / 64; ++i) { sfl += rfl[i]; sgt2 += rgt[i]; svp += rvp[i]; }
        partS[b * SLICES + slice] = make_float4(sfl, sgt2, __int_as_float(svp), 0.f);
    }
    if (tid < NGT) {
        keysP[((size_t)(b * NGT + tid)) * SLICES + slice] = skey[tid];
    }
}

// ---------- Pass B: single block; scatter corrections + per-image scalars +
// ---------- final reduction. 16 waves, wave-per-image, 2 rounds. No atomics. ----------

__global__ __launch_bounds__(1024) void passB(
    const float* __restrict__ pred, const float* __restrict__ gt,
    const unsigned long long* __restrict__ keysP,
    const float4* __restrict__ partS,
    float* __restrict__ out)
{
    const int tid = threadIdx.x;
    const int lane = tid & 63;
    const int wv = tid >> 6;          // 0..15

    __shared__ float4 sgt[16][NGT];           // 16 KiB, wave-private rows
    __shared__ unsigned cn_list[16][NGT];     // 4 KiB, wave-private rows
    __shared__ float clsL[NB], regL[NB];
    __shared__ int npL[NB];

    #pragma unroll
    for (int r = 0; r < 2; ++r) {
        const int b = r * 16 + wv;

        // gt boxes for this image (wave-private LDS row; no block sync needed)
        const float4* gtb = (const float4*)(gt + (size_t)b * NGT * 4);
        float4 gj = gtb[lane];
        sgt[wv][lane] = gj;

        // per-gt key = max over 64 slices (lane == gt index)
        const unsigned long long* kp = keysP + ((size_t)(b * NGT + lane)) * SLICES;
        const ulonglong2* kp2 = (const ulonglong2*)kp;
        unsigned long long key = 0ULL;
        #pragma unroll
        for (int s = 0; s < SLICES / 2; ++s) {
            ulonglong2 kk = kp2[s];
            key = (kk.x > key) ? kk.x : key;
            key = (kk.y > key) ? kk.y : key;
        }

        float miou = __uint_as_float((unsigned)(key >> 32));
        unsigned n = ~((unsigned)(key & 0xFFFFFFFFULL));
        bool qual = miou > SCAT_THR;   // key==0 -> miou=0 -> false

        // dedupe: keep first qualifying lane per pred index (ref .at[].max semantics)
        bool unique = qual;
        for (int j2 = 0; j2 < NGT; ++j2) {
            unsigned bn = __shfl(n, j2);
            int bq = __shfl((int)qual, j2);
            if (bq && j2 < lane && bn == n) unique = false;
        }
        unsigned long long mask = __ballot(unique ? 1 : 0);
        int NC = __popcll(mask);
        int slot = __popcll(mask & ((1ULL << lane) - 1ULL));
        if (unique) cn_list[wv][slot] = n;

        // candidate-parallel: lane l recomputes candidate l's full best_gt argmax
        float cx = 0.f, cy = 0.f, w = 0.f, h = 0.f, obj = 0.f;
        if (lane < NC) {
            const float* p = pred + (size_t)b * NPRED * 5 + (size_t)cn_list[wv][lane] * 5;
            cx = p[0]; cy = p[1]; w = p[2]; h = p[3]; obj = p[4];
        }
        float px1 = __fsub_rn(cx, __fmul_rn(w, 0.5f));
        float py1 = __fsub_rn(cy, __fmul_rn(h, 0.5f));
        float px2 = __fadd_rn(cx, __fmul_rn(w, 0.5f));
        float py2 = __fadd_rn(cy, __fmul_rn(h, 0.5f));
        float area_p = __fmul_rn(__fsub_rn(px2, px1), __fsub_rn(py2, py1));

        float bv = 0.f; int bj = 0;
        #pragma unroll 4
        for (int j = 0; j < NGT; ++j) {
            float4 g = sgt[wv][j];   // uniform -> broadcast
            float x1 = fmaxf(px1, g.x), y1 = fmaxf(py1, g.y);
            float x2 = fminf(px2, g.z), y2 = fminf(py2, g.w);
            float dx = fmaxf(__fsub_rn(x2, x1), 0.f);
            float dy = fmaxf(__fsub_rn(y2, y1), 0.f);
            float inter = __fmul_rn(dx, dy);
            if (inter > 0.f) {   // identical op sequence to passA
                float ag = __fmul_rn(__fsub_rn(g.z, g.x), __fsub_rn(g.w, g.y));
                float uni = __fsub_rn(__fadd_rn(area_p, ag), inter);
                float iou = __fdiv_rn(inter, fmaxf(uni, EPSF));
                if (iou > bv) { bv = iou; bj = j; }   // strict > == np.argmax first-max
            }
        }

        double add_fl = 0.0, add_gt = 0.0;
        int add_v = 0, add_p = 0;
        if (lane < NC && !(bv > POS_THR)) {   // passA counted non-pos: flip to pos
            bool was_neg = bv < NEG_THR;      // == valid0 in passA
            float f1 = focal_shared(obj, true);
            float f0 = focal_shared(obj, false);
            add_fl = (double)f1 - (was_neg ? (double)f0 : 0.0);
            add_v = was_neg ? 0 : 1;
            add_p = 1;
            float4 gb = sgt[wv][bj];
            add_gt = (double)giou_term(px1, py1, px2, py2, gb.x, gb.y, gb.z, gb.w);
        }

        // per-slice partial sums for this image (lane == slice index)
        float4 ps = partS[b * SLICES + lane];
        double sfl = (double)ps.x;
        double sgt2 = (double)ps.y;
        int vpk = __float_as_int(ps.z);
        int sv = vpk & 0xFFFF;        // unpack BEFORE summing (sum can exceed 16 bits)
        int sp = vpk >> 16;

        sfl += add_fl; sgt2 += add_gt; sv += add_v; sp += add_p;

        for (int off = 32; off; off >>= 1) {
            sfl  += __shfl_down(sfl, off);
            sgt2 += __shfl_down(sgt2, off);
            sv   += __shfl_down(sv, off);
            sp   += __shfl_down(sp, off);
        }

        if (lane == 0) {
            clsL[b] = (sv > 0) ? (float)(sfl / (double)(sv > 1 ? sv : 1)) : 0.f;
            regL[b] = (sp > 0) ? (float)(sgt2 / (double)(sp > 1 ? sp : 1)) : 0.f;
            npL[b] = sp;
        }
    }

    __syncthreads();

    if (wv == 0) {
        float cv = (lane < NB) ? clsL[lane] : 0.f;
        float rv = (lane < NB) ? regL[lane] : 0.f;
        int   nv = (lane < NB) ? npL[lane] : 0;
        for (int off = 32; off; off >>= 1) {
            cv += __shfl_down(cv, off);
            rv += __shfl_down(rv, off);
            nv += __shfl_down(nv, off);
        }
        if (lane == 0) {
            float num_pos = fmaxf((float)nv, 1.f);
            out[0] = cv / (float)NB + 2.0f * (rv / num_pos * (float)NB);
        }
    }
}

// ---------- launcher: 2 dispatches, zero memsets ----------

extern "C" void kernel_launch(void* const* d_in, const int* in_sizes, int n_in,
                              void* d_out, int out_size, void* d_ws, size_t ws_size,
                              hipStream_t stream) {
    const float* pred = (const float*)d_in[0];   // (32, 65536, 5) f32
    const float* gt   = (const float*)d_in[1];   // (32, 64, 4) f32
    float* out = (float*)d_out;

    char* ws = (char*)d_ws;
    unsigned long long* keysP = (unsigned long long*)(ws + 0);      // 32*64*64*8 = 1 MiB
    float4* partS = (float4*)(ws + (size_t)NB * NGT * SLICES * 8);  // 32*64*16 = 32 KiB
    // every workspace byte used is written unconditionally by passA before passB
    // reads it -> no init dispatch needed, poison-safe.

    dim3 gridA(SLICES, NB);
    passA<<<gridA, BLK, 0, stream>>>(pred, gt, keysP, partS);
    passB<<<1, 1024, 0, stream>>>(pred, gt, keysP, partS, out);
}

// Round 2
// 114.027 us; speedup vs baseline: 1.3523x; 1.3523x over previous
//
#include <hip/hip_runtime.h>

#define NB 32
#define NPRED 65536
#define NGT 64
#define BLK 256
#define SLICES 64
#define PPT 4                  // preds per thread; block covers 1024 preds
#define NCB 128                // cumulative bins of 5px
#define CBIN_SCALE 0.2f        // 1/5

#define POS_THR 0.5f
#define NEG_THR 0.4f
#define SCAT_THR 0.1f
#define EPSF 1e-6f

// ---------- exact-op helpers ----------
// Comparison-feeding arithmetic (iou) must be bit-exact vs NumPy fp32 (no FMA
// contraction, IEEE div). Sum-only terms (focal/giou weights) tolerate ulp drift.

__device__ __forceinline__ int cbin(float x) {
    int bi = (int)(x * CBIN_SCALE);         // trunc; monotone non-decreasing
    return max(0, min(NCB - 1, bi));        // clamp keeps monotone -> superset safe
}

__device__ __forceinline__ float focal_shared(float l, bool pos) {
    float e  = expf(-fabsf(l));
    float lg = log1pf(e);
    float rp = 1.f / (1.f + e);              // sigmoid(|l|)
    float p  = (l >= 0.f) ? rp : (1.f - rp); // sigmoid(l); sum-only term
    if (pos) { float q = 1.f - p; return 0.25f * q * q * ((fmaxf(l, 0.f) - l) + lg); }
    return 0.75f * p * p * (fmaxf(l, 0.f) + lg);
}

__device__ __forceinline__ float giou_term(float px1, float py1, float px2, float py2,
                                           float gx1, float gy1, float gx2, float gy2) {
    float x1 = fmaxf(px1, gx1), y1 = fmaxf(py1, gy1);
    float x2 = fminf(px2, gx2), y2 = fminf(py2, gy2);
    float dx = fmaxf(__fsub_rn(x2, x1), 0.f);
    float dy = fmaxf(__fsub_rn(y2, y1), 0.f);
    float inter = __fmul_rn(dx, dy);
    float ap = __fmul_rn(__fsub_rn(px2, px1), __fsub_rn(py2, py1));
    float ag = __fmul_rn(__fsub_rn(gx2, gx1), __fsub_rn(gy2, gy1));
    float uni = __fsub_rn(__fadd_rn(ap, ag), inter);
    float iou = __fdiv_rn(inter, fmaxf(uni, EPSF));
    float ex1 = fminf(px1, gx1), ey1 = fminf(py1, gy1);
    float ex2 = fmaxf(px2, gx2), ey2 = fmaxf(py2, gy2);
    float enc = __fmul_rn(__fsub_rn(ex2, ex1), __fsub_rn(ey2, ey1));
    float giou = __fsub_rn(iou, __fdiv_rn(__fsub_rn(enc, uni), fmaxf(enc, EPSF)));
    return __fsub_rn(1.f, giou);
}

// ---------- Pass A: per-slice partials, NO global atomics, NO pre-zero ----------
// keysP layout: [NB][SLICES][NGT] ullong (every entry written unconditionally;
//               contiguous 512B store per block, coalesced 512B loads in passB)
// partS layout: [NB][SLICES] float4 {sum_fl, sum_gt, bitcast(v|p<<16), 0}
// done: zeroed by block (0,0) -- stream ordering makes it visible to passB.

__global__ __launch_bounds__(BLK) void passA(
    const float* __restrict__ pred, const float* __restrict__ gt,
    unsigned long long* __restrict__ keysP,
    float4* __restrict__ partS,
    unsigned* __restrict__ done)
{
    const int b = blockIdx.y;
    const int slice = blockIdx.x;
    const int tid = threadIdx.x;
    const int lane = tid & 63;
    const int wv = tid >> 6;

    if (b == 0 && slice == 0 && tid == 0) *done = 0u;   // replaces memset dispatch

    // SoA gt (65th entry = zero dummy for branchless inline slots)
    __shared__ float sgx1[NGT + 1], sgy1[NGT + 1], sgx2[NGT + 1], sgy2[NGT + 1], sgar[NGT + 1];
    __shared__ unsigned long long skey[NGT];       // 512 B
    // cumulative candidate masks: [0]=le_x1 (prefix), [1]=ge_x2 (suffix),
    //                             [2]=le_y1 (prefix), [3]=ge_y2 (suffix)
    __shared__ unsigned long long cums[4][NCB];    // 4 KiB
    __shared__ float rfl[BLK / 64], rgt[BLK / 64];
    __shared__ int rvp[BLK / 64];

    // ---- pred loads first: 5 aligned float4 per thread, in flight during setup ----
    const unsigned base_n = (unsigned)(slice * (BLK * PPT));
    const float4* src4 = (const float4*)(pred + (size_t)b * NPRED * 5 + (size_t)base_n * 5)
                         + (size_t)tid * 5;
    float4 q0 = src4[0], q1 = src4[1], q2 = src4[2], q3 = src4[3], q4 = src4[4];

    // ---- gt setup ----
    const float4* gtb = (const float4*)(gt + (size_t)b * NGT * 4);
    float4 gmine;
    if (tid < NGT) gmine = gtb[tid];
    // zero the 4 point arrays (512 ullong, 2 per thread)
    ((unsigned long long*)cums)[tid] = 0ULL;
    ((unsigned long long*)cums)[tid + BLK] = 0ULL;
    if (tid < NGT) {
        sgx1[tid] = gmine.x; sgy1[tid] = gmine.y;
        sgx2[tid] = gmine.z; sgy2[tid] = gmine.w;
        sgar[tid] = __fmul_rn(__fsub_rn(gmine.z, gmine.x), __fsub_rn(gmine.w, gmine.y));
        skey[tid] = 0ULL;
    } else if (tid == NGT) {
        sgx1[NGT] = 0.f; sgy1[NGT] = 0.f; sgx2[NGT] = 0.f; sgy2[NGT] = 0.f; sgar[NGT] = 0.f;
    }
    __syncthreads();

    // point inserts (wave 0 only)
    if (tid < NGT) {
        unsigned long long bit = 1ULL << tid;
        atomicOr(&cums[0][cbin(gmine.x)], bit);   // gx1 -> prefix array
        atomicOr(&cums[1][cbin(gmine.z)], bit);   // gx2 -> suffix array
        atomicOr(&cums[2][cbin(gmine.y)], bit);   // gy1 -> prefix array
        atomicOr(&cums[3][cbin(gmine.w)], bit);   // gy2 -> suffix array
    }
    __syncthreads();

    // wave-parallel cumulative OR: wave wv scans array wv (128 bins, 2/lane).
    {
        unsigned long long v0 = cums[wv][2 * lane];
        unsigned long long v1 = cums[wv][2 * lane + 1];
        unsigned long long v = v0 | v1;
        if ((wv & 1) == 0) {
            // prefix (le): inclusive scan low->high
            #pragma unroll
            for (int off = 1; off < 64; off <<= 1) {
                unsigned long long t = __shfl_up(v, off);
                if (lane >= off) v |= t;
            }
            unsigned long long prev = __shfl_up(v, 1);
            if (lane == 0) prev = 0ULL;
            cums[wv][2 * lane]     = prev | v0;
            cums[wv][2 * lane + 1] = v;
        } else {
            // suffix (ge): inclusive scan high->low
            #pragma unroll
            for (int off = 1; off < 64; off <<= 1) {
                unsigned long long t = __shfl_down(v, off);
                if (lane + off < 64) v |= t;
            }
            unsigned long long nxt = __shfl_down(v, 1);
            if (lane == 63) nxt = 0ULL;
            cums[wv][2 * lane]     = v;
            cums[wv][2 * lane + 1] = v1 | nxt;
        }
    }
    __syncthreads();

    // ---- unpack rows: thread t owns preds 4t..4t+3 (stride-5 in the 20 floats) ----
    const float cxa[PPT] = {q0.x, q1.y, q2.z, q3.w};
    const float cya[PPT] = {q0.y, q1.z, q2.w, q4.x};
    const float wa [PPT] = {q0.z, q1.w, q3.x, q4.y};
    const float ha [PPT] = {q0.w, q2.x, q3.y, q4.z};
    const float oba[PPT] = {q1.x, q2.y, q3.z, q4.w};

    float acc_fl = 0.f, acc_gt = 0.f;
    int acc_vp = 0;   // valid count | pos count<<16

    #pragma unroll
    for (int i = 0; i < PPT; ++i) {
        const float px1 = __fsub_rn(cxa[i], __fmul_rn(wa[i], 0.5f));
        const float py1 = __fsub_rn(cya[i], __fmul_rn(ha[i], 0.5f));
        const float px2 = __fadd_rn(cxa[i], __fmul_rn(wa[i], 0.5f));
        const float py2 = __fadd_rn(cya[i], __fmul_rn(ha[i], 0.5f));
        const float area_p = __fmul_rn(__fsub_rn(px2, px1), __fsub_rn(py2, py1));

        // 4-probe candidate mask (superset of true overlaps; exact gate below)
        unsigned long long m = (cums[1][cbin(px1)] & cums[0][cbin(px2)])
                             & (cums[3][cbin(py1)] & cums[2][cbin(py2)]);

        const unsigned n = base_n + (unsigned)(PPT * tid + i);
        const unsigned long long nkey = (unsigned long long)(~n);

        float best_iou = 0.f;   // zero row -> argmax 0, matches np.argmax
        int best_j = 0;

        // branchless inline-2: dummy index 64 (zero box) -> inter=0 -> no-op
        int j0 = NGT, j1 = NGT;
        if (m) { j0 = __ffsll(m) - 1; m &= m - 1; }
        if (m) { j1 = __ffsll(m) - 1; m &= m - 1; }
        {
            float ax1 = sgx1[j0], ay1 = sgy1[j0], ax2 = sgx2[j0], ay2 = sgy2[j0], aga = sgar[j0];
            float bx1 = sgx1[j1], by1 = sgy1[j1], bx2 = sgx2[j1], by2 = sgy2[j1], agb = sgar[j1];
            float x1 = fmaxf(px1, ax1), y1 = fmaxf(py1, ay1);
            float x2 = fminf(px2, ax2), y2 = fminf(py2, ay2);
            float dx = fmaxf(__fsub_rn(x2, x1), 0.f);
            float dy = fmaxf(__fsub_rn(y2, y1), 0.f);
            float inter = __fmul_rn(dx, dy);
            float uni = __fsub_rn(__fadd_rn(area_p, aga), inter);
            float iou = __fdiv_rn(inter, fmaxf(uni, EPSF));
            iou = (inter > 0.f) ? iou : 0.f;
            if (iou > best_iou) { best_iou = iou; best_j = j0; }
            if (iou > SCAT_THR)
                atomicMax(&skey[j0], (((unsigned long long)__float_as_uint(iou)) << 32) | nkey);

            float X1 = fmaxf(px1, bx1), Y1 = fmaxf(py1, by1);
            float X2 = fminf(px2, bx2), Y2 = fminf(py2, by2);
            float dX = fmaxf(__fsub_rn(X2, X1), 0.f);
            float dY = fmaxf(__fsub_rn(Y2, Y1), 0.f);
            float interB = __fmul_rn(dX, dY);
            float uniB = __fsub_rn(__fadd_rn(area_p, agb), interB);
            float iouB = __fdiv_rn(interB, fmaxf(uniB, EPSF));
            iouB = (interB > 0.f) ? iouB : 0.f;
            if (iouB > best_iou) { best_iou = iouB; best_j = j1; }
            if (iouB > SCAT_THR)
                atomicMax(&skey[j1], (((unsigned long long)__float_as_uint(iouB)) << 32) | nkey);
        }

        // rare remainder (2-way unrolled)
        while (m) {
            int ja = __ffsll(m) - 1; m &= m - 1;
            int jb = -1;
            if (m) { jb = __ffsll(m) - 1; m &= m - 1; }
            int jbc = (jb >= 0) ? jb : NGT;
            float ax1 = sgx1[ja], ay1 = sgy1[ja], ax2 = sgx2[ja], ay2 = sgy2[ja], aga = sgar[ja];
            float bx1 = sgx1[jbc], by1 = sgy1[jbc], bx2 = sgx2[jbc], by2 = sgy2[jbc], agb = sgar[jbc];
            {
                float x1 = fmaxf(px1, ax1), y1 = fmaxf(py1, ay1);
                float x2 = fminf(px2, ax2), y2 = fminf(py2, ay2);
                float dx = fmaxf(__fsub_rn(x2, x1), 0.f);
                float dy = fmaxf(__fsub_rn(y2, y1), 0.f);
                float inter = __fmul_rn(dx, dy);
                if (inter > 0.f) {
                    float uni = __fsub_rn(__fadd_rn(area_p, aga), inter);
                    float iou = __fdiv_rn(inter, fmaxf(uni, EPSF));
                    if (iou > best_iou) { best_iou = iou; best_j = ja; }
                    if (iou > SCAT_THR)
                        atomicMax(&skey[ja], (((unsigned long long)__float_as_uint(iou)) << 32) | nkey);
                }
            }
            if (jb >= 0) {
                float x1 = fmaxf(px1, bx1), y1 = fmaxf(py1, by1);
                float x2 = fminf(px2, bx2), y2 = fminf(py2, by2);
                float dx = fmaxf(__fsub_rn(x2, x1), 0.f);
                float dy = fmaxf(__fsub_rn(y2, y1), 0.f);
                float inter = __fmul_rn(dx, dy);
                if (inter > 0.f) {
                    float uni = __fsub_rn(__fadd_rn(area_p, agb), inter);
                    float iou = __fdiv_rn(inter, fmaxf(uni, EPSF));
                    if (iou > best_iou) { best_iou = iou; best_j = jb; }
                    if (iou > SCAT_THR)
                        atomicMax(&skey[jb], (((unsigned long long)__float_as_uint(iou)) << 32) | nkey);
                }
            }
        }

        const bool pos0   = best_iou > POS_THR;
        const bool negf   = best_iou < NEG_THR;
        const bool valid0 = pos0 || negf;
        if (valid0) acc_fl += focal_shared(oba[i], pos0);
        if (pos0) {
            acc_gt += giou_term(px1, py1, px2, py2,
                                sgx1[best_j], sgy1[best_j], sgx2[best_j], sgy2[best_j]);
        }
        acc_vp += (valid0 ? 1 : 0) | (pos0 ? 0x10000 : 0);
    }

    // one reduction + plain per-slice stores (no global atomics, no pre-zeroed ws)
    for (int off = 32; off; off >>= 1) {
        acc_fl += __shfl_down(acc_fl, off);
        acc_gt += __shfl_down(acc_gt, off);
        acc_vp += __shfl_down(acc_vp, off);
    }
    if (lane == 0) { rfl[wv] = acc_fl; rgt[wv] = acc_gt; rvp[wv] = acc_vp; }
    __syncthreads();   // also orders all skey LDS atomics before the drain
    if (tid == 0) {
        float sfl = 0.f, sgt2 = 0.f; int svp = 0;
        #pragma unroll
        for (int i = 0; i < BLK / 64; ++i) { sfl += rfl[i]; sgt2 += rgt[i]; svp += rvp[i]; }
        partS[b * SLICES + slice] = make_float4(sfl, sgt2, __int_as_float(svp), 0.f);
    }
    if (tid < NGT) {
        // [b][slice][gt]: contiguous 512B per block
        keysP[((size_t)b * SLICES + slice) * NGT + tid] = skey[tid];
    }
}

// ---------- Pass B: 32 blocks (one per image), 64 lanes; scatter corrections +
// ---------- per-image scalars + last-block final reduction. No memset needed. ----------

__global__ __launch_bounds__(64) void passB(
    const float* __restrict__ pred, const float* __restrict__ gt,
    const unsigned long long* __restrict__ keysP,
    const float4* __restrict__ partS,
    float* __restrict__ cls_b, float* __restrict__ reg_b, int* __restrict__ npos_b,
    unsigned* __restrict__ done, float* __restrict__ out)
{
    const int b = blockIdx.x;
    const int lane = threadIdx.x;   // one wave; lane == gt index initially

    __shared__ float4 sgt[NGT];
    __shared__ unsigned cn_list[NGT];

    const float4* gtb = (const float4*)(gt + (size_t)b * NGT * 4);
    float4 gj = gtb[lane];
    sgt[lane] = gj;

    // per-gt key = max over 64 slices; [b][slice][gt] -> each iter is one
    // coalesced 512B wave-load
    const unsigned long long* kp = keysP + (size_t)b * SLICES * NGT + lane;
    unsigned long long key = 0ULL;
    #pragma unroll 16
    for (int s = 0; s < SLICES; ++s) {
        unsigned long long k = kp[(size_t)s * NGT];
        key = (k > key) ? k : key;
    }

    float miou = __uint_as_float((unsigned)(key >> 32));
    unsigned n = ~((unsigned)(key & 0xFFFFFFFFULL));
    bool qual = miou > SCAT_THR;   // key==0 -> miou=0 -> false

    // dedupe: keep first qualifying lane per pred index (ref .at[].max semantics)
    bool unique = qual;
    for (int j2 = 0; j2 < NGT; ++j2) {
        unsigned bn = __shfl(n, j2);
        int bq = __shfl((int)qual, j2);
        if (bq && j2 < lane && bn == n) unique = false;
    }
    unsigned long long mask = __ballot(unique ? 1 : 0);
    int NC = __popcll(mask);
    int slot = __popcll(mask & ((1ULL << lane) - 1ULL));
    if (unique) cn_list[slot] = n;
    __syncthreads();

    // candidate-parallel: lane l recomputes candidate l's full best_gt argmax
    float cx = 0.f, cy = 0.f, w = 0.f, h = 0.f, obj = 0.f;
    if (lane < NC) {
        const float* p = pred + (size_t)b * NPRED * 5 + (size_t)cn_list[lane] * 5;
        cx = p[0]; cy = p[1]; w = p[2]; h = p[3]; obj = p[4];
    }
    float px1 = __fsub_rn(cx, __fmul_rn(w, 0.5f));
    float py1 = __fsub_rn(cy, __fmul_rn(h, 0.5f));
    float px2 = __fadd_rn(cx, __fmul_rn(w, 0.5f));
    float py2 = __fadd_rn(cy, __fmul_rn(h, 0.5f));
    float area_p = __fmul_rn(__fsub_rn(px2, px1), __fsub_rn(py2, py1));

    float bv = 0.f; int bj = 0;
    #pragma unroll 4
    for (int j = 0; j < NGT; ++j) {
        float4 g = sgt[j];   // uniform -> broadcast
        float x1 = fmaxf(px1, g.x), y1 = fmaxf(py1, g.y);
        float x2 = fminf(px2, g.z), y2 = fminf(py2, g.w);
        float dx = fmaxf(__fsub_rn(x2, x1), 0.f);
        float dy = fmaxf(__fsub_rn(y2, y1), 0.f);
        float inter = __fmul_rn(dx, dy);
        if (inter > 0.f) {   // identical op sequence to passA
            float ag = __fmul_rn(__fsub_rn(g.z, g.x), __fsub_rn(g.w, g.y));
            float uni = __fsub_rn(__fadd_rn(area_p, ag), inter);
            float iou = __fdiv_rn(inter, fmaxf(uni, EPSF));
            if (iou > bv) { bv = iou; bj = j; }   // strict > == np.argmax first-max
        }
    }

    double add_fl = 0.0, add_gt = 0.0;
    int add_v = 0, add_p = 0;
    if (lane < NC && !(bv > POS_THR)) {   // passA counted non-pos: flip to pos
        bool was_neg = bv < NEG_THR;      // == valid0 in passA
        float f1 = focal_shared(obj, true);
        float f0 = focal_shared(obj, false);
        add_fl = (double)f1 - (was_neg ? (double)f0 : 0.0);
        add_v = was_neg ? 0 : 1;
        add_p = 1;
        float4 gb = sgt[bj];
        add_gt = (double)giou_term(px1, py1, px2, py2, gb.x, gb.y, gb.z, gb.w);
    }

    // per-slice partial sums for this image (lane == slice index)
    float4 ps = partS[b * SLICES + lane];
    double sfl = (double)ps.x + add_fl;
    double sgt2 = (double)ps.y + add_gt;
    int vpk = __float_as_int(ps.z);
    int sv = (vpk & 0xFFFF) + add_v;   // unpack BEFORE summing (sum exceeds 16 bits)
    int sp = (vpk >> 16) + add_p;

    for (int off = 32; off; off >>= 1) {
        sfl  += __shfl_down(sfl, off);
        sgt2 += __shfl_down(sgt2, off);
        sv   += __shfl_down(sv, off);
        sp   += __shfl_down(sp, off);
    }

    if (lane == 0) {
        cls_b[b] = (sv > 0) ? (float)(sfl / (double)(sv > 1 ? sv : 1)) : 0.f;
        reg_b[b] = (sp > 0) ? (float)(sgt2 / (double)(sp > 1 ? sp : 1)) : 0.f;
        npos_b[b] = sp;
    }

    // last-block final reduction (device-scope atomics + fences per G16)
    __threadfence();
    unsigned t = 0;
    if (lane == 0) t = atomicAdd(done, 1u);
    t = __shfl(t, 0);
    if (t == NB - 1) {
        __threadfence();
        volatile float* vc = cls_b;
        volatile float* vr = reg_b;
        volatile int*   vn = npos_b;
        float cv = (lane < NB) ? vc[lane] : 0.f;
        float rv = (lane < NB) ? vr[lane] : 0.f;
        int   nv = (lane < NB) ? vn[lane] : 0;
        for (int off = 32; off; off >>= 1) {
            cv += __shfl_down(cv, off);
            rv += __shfl_down(rv, off);
            nv += __shfl_down(nv, off);
        }
        if (lane == 0) {
            float num_pos = fmaxf((float)nv, 1.f);
            out[0] = cv / (float)NB + 2.0f * (rv / num_pos * (float)NB);
        }
    }
}

// ---------- launcher: 2 dispatches, zero memsets ----------

extern "C" void kernel_launch(void* const* d_in, const int* in_sizes, int n_in,
                              void* d_out, int out_size, void* d_ws, size_t ws_size,
                              hipStream_t stream) {
    const float* pred = (const float*)d_in[0];   // (32, 65536, 5) f32
    const float* gt   = (const float*)d_in[1];   // (32, 64, 4) f32
    float* out = (float*)d_out;

    char* ws = (char*)d_ws;
    unsigned long long* keysP = (unsigned long long*)(ws + 0);      // 32*64*64*8 = 1 MiB
    float4* partS = (float4*)(ws + (size_t)NB * SLICES * NGT * 8);  // 32*64*16 = 32 KiB
    char* tail = ws + (size_t)NB * SLICES * NGT * 8 + (size_t)NB * SLICES * 16;
    float* cls_b   = (float*)(tail);                                // 128 B
    float* reg_b   = (float*)(tail + 128);                          // 128 B
    int* npos_b    = (int*)(tail + 256);                            // 128 B
    unsigned* done = (unsigned*)(tail + 384);                       // 4 B
    // every workspace byte used is written before it is read within one
    // iteration (done is zeroed by passA block (0,0)) -> no init dispatch,
    // poison-safe.

    dim3 gridA(SLICES, NB);
    passA<<<gridA, BLK, 0, stream>>>(pred, gt, keysP, partS, done);
    passB<<<NB, 64, 0, stream>>>(pred, gt, keysP, partS,
                                 cls_b, reg_b, npos_b, done, out);
}